// Round 1
// baseline (251.127 us; speedup 1.0000x reference)
//
#include <hip/hip_runtime.h>
#include <math.h>

// out[i][j] = | prod_w ( cos((x[i][w]+theta[w])/2) * cos((y[j][w]+theta[w])/2)
//                      - sin((x[i][w]+theta[w])/2) * sin((y[j][w]+theta[w])/2) ) |
//           = | prod_w cos((x[i][w]+y[j][w])/2 + theta[w]) |
// Derivation: RX(x)RX(th)=RX(x+th) -> product state; CNOT ladder is a fixed basis
// permutation P and the reference uses a plain (non-conjugated) bilinear form, so
// (P a)·(P b) = a·b — the CNOTs cancel. Inner product factorizes per wire.

#define BM 16   // output rows per block (i / x-rows)
#define BN 256  // output cols per block (j / y-rows)

__global__ __launch_bounds__(256) void qk_main(
    const float* __restrict__ x, const float* __restrict__ y,
    const float* __restrict__ theta, float* __restrict__ out,
    int Bx, int By)
{
    // Transposed trig tiles: [0..3] = cos per wire, [4..7] = sin per wire.
    __shared__ float at[8][BM];   // A tile (x rows)
    __shared__ float bt[8][BN];   // B tile (y rows)

    const int tid = threadIdx.x;
    const int i0 = blockIdx.y * BM;
    const int j0 = blockIdx.x * BN;

    // half-theta (wave-uniform scalar loads)
    const float th0 = 0.5f * theta[0];
    const float th1 = 0.5f * theta[1];
    const float th2 = 0.5f * theta[2];
    const float th3 = 0.5f * theta[3];

    // B tile trig: one y-row per thread, coalesced float4 load.
    {
        const float4 y4 = ((const float4*)y)[j0 + tid];
        float s, c;
        __sincosf(0.5f * y4.x + th0, &s, &c); bt[0][tid] = c; bt[4][tid] = s;
        __sincosf(0.5f * y4.y + th1, &s, &c); bt[1][tid] = c; bt[5][tid] = s;
        __sincosf(0.5f * y4.z + th2, &s, &c); bt[2][tid] = c; bt[6][tid] = s;
        __sincosf(0.5f * y4.w + th3, &s, &c); bt[3][tid] = c; bt[7][tid] = s;
    }
    // A tile trig: threads 0..15, one x-row each.
    if (tid < BM) {
        const float4 x4 = ((const float4*)x)[i0 + tid];
        float s, c;
        __sincosf(0.5f * x4.x + th0, &s, &c); at[0][tid] = c; at[4][tid] = s;
        __sincosf(0.5f * x4.y + th1, &s, &c); at[1][tid] = c; at[5][tid] = s;
        __sincosf(0.5f * x4.z + th2, &s, &c); at[2][tid] = c; at[6][tid] = s;
        __sincosf(0.5f * x4.w + th3, &s, &c); at[3][tid] = c; at[7][tid] = s;
    }
    __syncthreads();

    const int tx = tid & 63;   // j sub-tile: 4 consecutive cols per thread
    const int ty = tid >> 6;   // i sub-tile: 4 consecutive rows per wave

    float acc[4][4];
    #pragma unroll
    for (int w = 0; w < 4; ++w) {
        // A fragments: wave-uniform (broadcast, conflict-free)
        const float4 ca = ((const float4*)&at[w][0])[ty];
        const float4 sa = ((const float4*)&at[w + 4][0])[ty];
        // B fragments: ds_read_b128, lane stride 16 B -> all 32 banks, conflict-free
        const float4 cb = ((const float4*)&bt[w][0])[tx];
        const float4 sb = ((const float4*)&bt[w + 4][0])[tx];

        const float cai[4] = {ca.x, ca.y, ca.z, ca.w};
        const float sai[4] = {sa.x, sa.y, sa.z, sa.w};
        const float cbj[4] = {cb.x, cb.y, cb.z, cb.w};
        const float sbj[4] = {sb.x, sb.y, sb.z, sb.w};

        #pragma unroll
        for (int i = 0; i < 4; ++i) {
            #pragma unroll
            for (int j = 0; j < 4; ++j) {
                const float t = fmaf(cai[i], cbj[j], -(sai[i] * sbj[j]));
                acc[i][j] = (w == 0) ? t : acc[i][j] * t;
            }
        }
    }

    // Coalesced float4 stores: 4 rows per thread.
    #pragma unroll
    for (int i = 0; i < 4; ++i) {
        const int row = i0 + ty * 4 + i;
        float4 o;
        o.x = fabsf(acc[i][0]);
        o.y = fabsf(acc[i][1]);
        o.z = fabsf(acc[i][2]);
        o.w = fabsf(acc[i][3]);
        ((float4*)&out[(size_t)row * By + j0])[tx] = o;
    }
}

extern "C" void kernel_launch(void* const* d_in, const int* in_sizes, int n_in,
                              void* d_out, int out_size, void* d_ws, size_t ws_size,
                              hipStream_t stream) {
    const float* x     = (const float*)d_in[0];
    const float* y     = (const float*)d_in[1];
    const float* theta = (const float*)d_in[2];
    float* out = (float*)d_out;

    const int Bx = in_sizes[0] / 4;  // 8192
    const int By = in_sizes[1] / 4;  // 8192

    dim3 grid(By / BN, Bx / BM);     // (32, 512)
    qk_main<<<grid, dim3(256), 0, stream>>>(x, y, theta, out, Bx, By);
}